// Round 9
// baseline (163.748 us; speedup 1.0000x reference)
//
#include <hip/hip_runtime.h>
#include <hip/hip_bf16.h>
#include <hip/hip_fp16.h>

// GCN 2-layer: N=50000 nodes, E=800000 edges, 128->128(relu)->64.
// CSR build: two-level LDS-binned partition (128-node buckets, no global
// atomics). GEMMs: fp16 MFMA 16x16x32, LDS-free, fragment-prepacked W.
// Node features stored CHUNK-MAJOR fp16 (32 feats = 64B per node-chunk) so
// each aggregation pass's gather working set (3.2MB) fits per-XCD L2 (4MB).
// agg: 1 wave/node, 4 edge-groups x 16 lanes, full-wave-uniform shuffles.

#define CHUNK 4096   // edges per partition chunk
#define BSHIFT 7
#define BSIZE 128    // nodes per bucket
#define BCAP 4096    // max edges per bucket held in LDS (avg ~2046, >40 sigma)

typedef unsigned int uint;
typedef _Float16 f16x8 __attribute__((ext_vector_type(8)));
typedef float f32x4 __attribute__((ext_vector_type(4)));

__device__ __forceinline__ float2 h2f(uint v) {
  __half2 h;
  __builtin_memcpy(&h, &v, 4);
  return __half22float2(h);
}

__device__ __forceinline__ uint f2h(float a, float b) {
  __half2 h = __halves2half2(__float2half_rn(a), __float2half_rn(b));
  uint r;
  __builtin_memcpy(&r, &h, 4);
  return r;
}

// int64-vs-int32 edge detection, computed per block (wave 0 ballot over the
// first 64 high words; node ids < 2^31 make this deterministic).
__device__ __forceinline__ int block_is64(const int* ei, int* s_is64) {
  if (threadIdx.x < 64) {
    unsigned long long m = __ballot(ei[2 * threadIdx.x + 1] != 0);
    if (threadIdx.x == 0) *s_is64 = (m == 0ULL) ? 1 : 0;
  }
  __syncthreads();
  return *s_is64;
}

// A1: per-chunk histogram over buckets (dst >> BSHIFT)
__global__ __launch_bounds__(256) void hist_k(const int* __restrict__ ei,
                                              int* __restrict__ gh,
                                              int E, int nchunk, int nbuck) {
  __shared__ int h[512];
  __shared__ int s_is64;
  int c = blockIdx.x;
  for (int i = threadIdx.x; i < 512; i += 256) h[i] = 0;
  int is64 = block_is64(ei, &s_is64);  // has a __syncthreads inside
  int base = c * CHUNK;
  int lim = min(CHUNK, E - base);
  for (int i = threadIdx.x; i < lim; i += 256) {
    int e = base + i;
    int d = is64 ? ei[2 * ((size_t)E + e)] : ei[(size_t)E + e];
    atomicAdd(&h[d >> BSHIFT], 1);
  }
  __syncthreads();
  for (int k = threadIdx.x; k < nbuck; k += 256) gh[k * nchunk + c] = h[k];
}

// A2a: per-bucket totals
__global__ __launch_bounds__(256) void tot_k(const int* __restrict__ gh,
                                             int* __restrict__ totals, int nchunk) {
  __shared__ int sd[256];
  int k = blockIdx.x;
  int s = 0;
  for (int i = threadIdx.x; i < nchunk; i += 256) s += gh[k * nchunk + i];
  sd[threadIdx.x] = s;
  __syncthreads();
  for (int o = 128; o > 0; o >>= 1) {
    if (threadIdx.x < o) sd[threadIdx.x] += sd[threadIdx.x + o];
    __syncthreads();
  }
  if (threadIdx.x == 0) totals[k] = sd[0];
}

// A2c: block k: bucketStart[k] (= sum totals[<k]) + scan of gh row k.
__global__ __launch_bounds__(256) void scanrow_k(int* __restrict__ gh,
                                                 const int* __restrict__ totals,
                                                 int* __restrict__ bucketStart,
                                                 int* __restrict__ offsets,
                                                 int nchunk, int nbuck, int N, int E) {
  __shared__ int st[256];
  int k = blockIdx.x;
  int t = threadIdx.x;
  int partial = 0;
  for (int i = t; i < k; i += 256) partial += totals[i];
  st[t] = partial;
  __syncthreads();
  for (int o = 128; o > 0; o >>= 1) {
    if (t < o) st[t] += st[t + o];
    __syncthreads();
  }
  int bs = st[0];
  if (t == 0) {
    bucketStart[k] = bs;
    if (k == nbuck - 1) { bucketStart[nbuck] = E; offsets[N] = E; }
  }
  __syncthreads();
  int x = (t < nchunk) ? gh[k * nchunk + t] : 0;
  st[t] = x;
  __syncthreads();
  int incl = x;
  for (int o = 1; o < 256; o <<= 1) {
    int add = (t >= o) ? st[t - o] : 0;
    __syncthreads();
    incl += add;
    st[t] = incl;
    __syncthreads();
  }
  if (t < nchunk) gh[k * nchunk + t] = bs + (incl - x);
}

// A3: partition edges into bucket-grouped tmp, packed (src16 | dstlow7<<16)
__global__ __launch_bounds__(256) void part_k(const int* __restrict__ ei,
                                              const int* __restrict__ gh,
                                              int* __restrict__ tmp,
                                              int E, int nchunk, int nbuck) {
  __shared__ int cur[512];
  __shared__ int s_is64;
  int c = blockIdx.x;
  for (int i = threadIdx.x; i < nbuck; i += 256) cur[i] = gh[i * nchunk + c];
  int is64 = block_is64(ei, &s_is64);
  int base = c * CHUNK;
  int lim = min(CHUNK, E - base);
  for (int i = threadIdx.x; i < lim; i += 256) {
    int e = base + i;
    int s, d;
    if (is64) {
      s = ei[2 * (size_t)e];
      d = ei[2 * ((size_t)E + e)];
    } else {
      s = ei[e];
      d = ei[(size_t)E + e];
    }
    int p = atomicAdd(&cur[d >> BSHIFT], 1);
    tmp[p] = s | ((d & (BSIZE - 1)) << 16);
  }
}

// B: one block per 128-node bucket: LDS count+scan -> offsets, dinv, csr_src
__global__ __launch_bounds__(256) void bucket_k(const int* __restrict__ tmp,
                                                const int* __restrict__ bucketStart,
                                                int* __restrict__ csr_src,
                                                int* __restrict__ offsets,
                                                float* __restrict__ dinv,
                                                int N) {
  __shared__ int ebuf[BCAP];
  __shared__ int cnt[BSIZE];
  __shared__ int st[256];
  __shared__ int lofs[BSIZE];
  int k = blockIdx.x;
  int b0 = bucketStart[k], b1 = bucketStart[k + 1];
  int sz = b1 - b0;
  int t = threadIdx.x;
  if (t < BSIZE) cnt[t] = 0;
  __syncthreads();
  bool inlds = (sz <= BCAP);
  if (inlds) {
    for (int i = t; i < sz; i += 256) {
      int v = tmp[b0 + i];
      ebuf[i] = v;
      atomicAdd(&cnt[v >> 16], 1);
    }
  } else {
    for (int i = t; i < sz; i += 256) atomicAdd(&cnt[tmp[b0 + i] >> 16], 1);
  }
  __syncthreads();
  int x = (t < BSIZE) ? cnt[t] : 0;
  st[t] = x;
  __syncthreads();
  int incl = x;
  for (int o = 1; o < 256; o <<= 1) {
    int add = (t >= o) ? st[t - o] : 0;
    __syncthreads();
    incl += add;
    st[t] = incl;
    __syncthreads();
  }
  int node = (k << BSHIFT) + t;
  if (t < BSIZE) {
    lofs[t] = incl - x;
    if (node < N) {
      offsets[node] = b0 + lofs[t];
      dinv[node] = rsqrtf((float)(x + 1));  // +1 self-loop
    }
  }
  __syncthreads();
  if (t < BSIZE) cnt[t] = lofs[t];  // reuse as cursor
  __syncthreads();
  if (inlds) {
    for (int i = t; i < sz; i += 256) {
      int v = ebuf[i];
      int p = atomicAdd(&cnt[v >> 16], 1);
      csr_src[b0 + p] = v & 0xFFFF;
    }
  } else {
    for (int i = t; i < sz; i += 256) {
      int v = tmp[b0 + i];
      int p = atomicAdd(&cnt[v >> 16], 1);
      csr_src[b0 + p] = v & 0xFFFF;
    }
  }
}

// ---- prep: both W's -> fragment-linear fp16 packs (one launch) ----
// P[(((t*NF + c)*64 + l)*8 + j)] = fp16( W[t*32 + (l>>4)*8 + j][c*16 + (l&15)] )
__global__ void prep2_k(const float* __restrict__ W1,
                        const float* __restrict__ W2,
                        _Float16* __restrict__ P) {
  int idx = blockIdx.x * blockDim.x + threadIdx.x;
  if (idx >= 24576) return;
  const float* W;
  _Float16* dst;
  int NC, li;
  if (idx < 16384) { W = W1; dst = P;        NC = 128; li = idx; }
  else             { W = W2; dst = P + 16384; NC = 64;  li = idx - 16384; }
  int NF = NC >> 4;
  int j = li & 7;
  int l = (li >> 3) & 63;
  int rest = li >> 9;
  int c = rest % NF;
  int t = rest / NF;
  int k = t * 32 + ((l >> 4) << 3) + j;
  int col = c * 16 + (l & 15);
  dst[li] = (_Float16)W[(size_t)k * NC + col];
}

// ---- MFMA GEMM: H(fp16, CHUNK-MAJOR) = dinv[row] * (X @ W[128,NC]) ----
// H layout: H[((col>>5)*M + row)*32 + (col&31)], i.e. 32-feat chunks.
// A16: A rows are fp16 chunk-major [((t*M)+row)*32 + k] (t = K-tile = chunk).
template <int NC, bool A16>
__global__ __launch_bounds__(256) void mfma_gemm_k(const void* __restrict__ Xv,
                                                   const _Float16* __restrict__ Wp,
                                                   const float* __restrict__ dinv,
                                                   _Float16* __restrict__ H, int M) {
  constexpr int NF = NC / 16;
  int lane = threadIdx.x & 63;
  int w = threadIdx.x >> 6;
  int row0 = blockIdx.x * 64 + w * 16;
  int arow = row0 + (lane & 15);
  bool av = arow < M;
  const uint4* wp = (const uint4*)Wp;

  f32x4 acc[NF];
#pragma unroll
  for (int c = 0; c < NF; ++c) acc[c] = (f32x4){0.f, 0.f, 0.f, 0.f};

#pragma unroll
  for (int t = 0; t < 4; ++t) {
    f16x8 a;
    if constexpr (A16) {
      const _Float16* yr =
          (const _Float16*)Xv + ((size_t)t * M + arow) * 32 + ((lane >> 4) << 3);
      uint4 araw = av ? *(const uint4*)yr : make_uint4(0u, 0u, 0u, 0u);
      __builtin_memcpy(&a, &araw, 16);
    } else {
      const float* xr =
          (const float*)Xv + (size_t)arow * 128 + ((lane >> 4) << 3) + t * 32;
      float4 lo = av ? *(const float4*)xr : make_float4(0.f, 0.f, 0.f, 0.f);
      float4 hi = av ? *(const float4*)(xr + 4) : make_float4(0.f, 0.f, 0.f, 0.f);
      a[0] = (_Float16)lo.x; a[1] = (_Float16)lo.y;
      a[2] = (_Float16)lo.z; a[3] = (_Float16)lo.w;
      a[4] = (_Float16)hi.x; a[5] = (_Float16)hi.y;
      a[6] = (_Float16)hi.z; a[7] = (_Float16)hi.w;
    }
#pragma unroll
    for (int c = 0; c < NF; ++c) {
      uint4 braw = wp[(t * NF + c) * 64 + lane];
      f16x8 b;
      __builtin_memcpy(&b, &braw, 16);
      acc[c] = __builtin_amdgcn_mfma_f32_16x16x32_f16(a, b, acc[c], 0, 0, 0);
    }
  }

  int rbase = row0 + ((lane >> 4) << 2);
#pragma unroll
  for (int r = 0; r < 4; ++r) {
    int row = rbase + r;
    if (row < M) {
      float di = dinv[row];
#pragma unroll
      for (int c = 0; c < NF; ++c) {
        // col = c*16 + (lane&15); chunk = col>>5 = c>>1
        size_t off = ((size_t)(c >> 1) * M + row) * 32 + (c & 1) * 16 + (lane & 15);
        H[off] = (_Float16)(di * acc[c][r]);
      }
    }
  }
}

// ---- Chunked aggregation: out = act( dinv_i*(h'_i + sum_src h'_src) + b ) ----
// hp: chunk-major fp16x2, 16 uints (=32 feats) per node-chunk.
// 1 wave per node; 4 edge-groups (g=lane>>4) x 16 feat-uints (j=lane&15).
// All shuffles execute at full-wave convergence. grid.x = nchunks * nblk.
template <bool RELU, bool OUT16>
__global__ __launch_bounds__(256) void agg_k(const uint* __restrict__ hp,
                                             const float* __restrict__ dinv,
                                             const int* __restrict__ offsets,
                                             const int* __restrict__ csr_src,
                                             const float* __restrict__ b,
                                             void* __restrict__ outv,
                                             int n, int nblk, int ncfull) {
  int wave = threadIdx.x >> 6;
  int lane = threadIdx.x & 63;
  int c = blockIdx.x / nblk;  // feature chunk (slow index -> L2 residency)
  int nb = blockIdx.x % nblk;
  int node = nb * 4 + wave;
  if (node >= n) return;
  int g = lane >> 4;
  int j = lane & 15;
  int beg = offsets[node], end = offsets[node + 1];
  int deg = end - beg;
  const uint* hc = hp + (size_t)c * n * 16;
  float ax = 0.f, ay = 0.f;
  if (g == 0) {  // self term, counted once
    float2 s = h2f(hc[(size_t)node * 16 + j]);
    ax = s.x; ay = s.y;
  }
  int sv = 0;
  if (lane < deg) sv = csr_src[beg + lane];
  int lim = deg < 64 ? deg : 64;
  int e0 = 0;
  for (; e0 + 8 <= lim; e0 += 8) {  // 8 edges per iter: 2 loads in flight
    int sA = __shfl(sv, e0 + g);
    int sB = __shfl(sv, e0 + 4 + g);
    uint uA = hc[(size_t)sA * 16 + j];
    uint uB = hc[(size_t)sB * 16 + j];
    float2 vA = h2f(uA), vB = h2f(uB);
    ax += vA.x + vB.x;
    ay += vA.y + vB.y;
  }
  for (; e0 < lim; e0 += 4) {  // tail, predicated (shfl at full wave)
    int idx = e0 + g;
    bool val = idx < lim;
    int s = __shfl(sv, val ? idx : 0);
    if (val) {
      float2 v = h2f(hc[(size_t)s * 16 + j]);
      ax += v.x; ay += v.y;
    }
  }
  for (int ee = beg + 64; ee < end; ee += 4) {  // deg>64 fallback (rare)
    int idx = ee + g;
    if (idx < end) {
      float2 v = h2f(hc[(size_t)csr_src[idx] * 16 + j]);
      ax += v.x; ay += v.y;
    }
  }
  // reduce across the 4 edge-groups (xor lane bits 4,5; full-wave uniform)
  ax += __shfl_xor(ax, 16); ay += __shfl_xor(ay, 16);
  ax += __shfl_xor(ax, 32); ay += __shfl_xor(ay, 32);
  if (g == 0) {
    float di = dinv[node];
    float2 bb = ((const float2*)b)[c * 16 + j];
    float ox = fmaf(di, ax, bb.x);
    float oy = fmaf(di, ay, bb.y);
    if (RELU) { ox = fmaxf(ox, 0.f); oy = fmaxf(oy, 0.f); }
    if (OUT16) {
      ((uint*)outv)[((size_t)c * n + node) * 16 + j] = f2h(ox, oy);  // chunk-major
    } else {
      ((float2*)outv)[(size_t)node * (ncfull >> 1) + c * 16 + j] =
          make_float2(ox, oy);  // row-major f32
    }
  }
}

extern "C" void kernel_launch(void* const* d_in, const int* in_sizes, int n_in,
                              void* d_out, int out_size, void* d_ws, size_t ws_size,
                              hipStream_t stream) {
  const float* x  = (const float*)d_in[0];
  const int*   ei = (const int*)d_in[1];
  const float* W1 = (const float*)d_in[2];
  const float* b1 = (const float*)d_in[3];
  const float* W2 = (const float*)d_in[4];
  const float* b2 = (const float*)d_in[5];
  float* out = (float*)d_out;

  const int N = in_sizes[0] / 128;   // 50000
  const int E = in_sizes[1] / 2;     // 800000
  const int NBUCK = (N + BSIZE - 1) >> BSHIFT;   // 391
  const int NCHUNK = (E + CHUNK - 1) / CHUNK;    // 196

  char* w = (char*)d_ws;
  size_t off = 0;
  auto alloc = [&](size_t bytes) -> void* {
    void* p = w + off;
    off = (off + bytes + 511) & ~(size_t)511;
    return p;
  };
  int*       gh      = (int*)alloc((size_t)NBUCK * NCHUNK * 4);
  int*       totals  = (int*)alloc((size_t)NBUCK * 4);
  int*       bstart  = (int*)alloc((size_t)(NBUCK + 1) * 4);
  int*       tmp     = (int*)alloc((size_t)E * 4);
  int*       offsets = (int*)alloc((size_t)(N + 1) * 4);
  float*     dinv    = (float*)alloc((size_t)N * 4);
  int*       csr_src = (int*)alloc((size_t)E * 4);
  _Float16*  pW      = (_Float16*)alloc(24576 * 2);      // W1 pack | W2 pack
  _Float16*  h1      = (_Float16*)alloc((size_t)N * 128 * 2);  // chunk-major
  _Float16*  y       = (_Float16*)alloc((size_t)N * 128 * 2);  // chunk-major
  _Float16*  h2      = (_Float16*)alloc((size_t)N * 64 * 2);   // chunk-major

  const int GB   = (N + 63) / 64;
  const int NBLK = (N + 3) / 4;  // 12500 node-blocks per chunk pass

  hist_k<<<NCHUNK, 256, 0, stream>>>(ei, gh, E, NCHUNK, NBUCK);
  tot_k<<<NBUCK, 256, 0, stream>>>(gh, totals, NCHUNK);
  scanrow_k<<<NBUCK, 256, 0, stream>>>(gh, totals, bstart, offsets, NCHUNK, NBUCK, N, E);
  part_k<<<NCHUNK, 256, 0, stream>>>(ei, gh, tmp, E, NCHUNK, NBUCK);
  bucket_k<<<NBUCK, 256, 0, stream>>>(tmp, bstart, csr_src, offsets, dinv, N);

  prep2_k<<<96, 256, 0, stream>>>(W1, W2, pW);

  mfma_gemm_k<128, false><<<GB, 256, 0, stream>>>(x, pW, dinv, h1, N);
  agg_k<true, true><<<4 * NBLK, 256, 0, stream>>>((const uint*)h1, dinv, offsets,
                                                  csr_src, b1, y, N, NBLK, 128);
  mfma_gemm_k<64, true><<<GB, 256, 0, stream>>>(y, pW + 16384, dinv, h2, N);
  agg_k<false, false><<<2 * NBLK, 256, 0, stream>>>((const uint*)h2, dinv, offsets,
                                                    csr_src, b2, out, N, NBLK, 64);
}

// Round 10
// 141.104 us; speedup vs baseline: 1.1605x; 1.1605x over previous
//
#include <hip/hip_runtime.h>
#include <hip/hip_bf16.h>
#include <hip/hip_fp16.h>

// GCN 2-layer: N=50000 nodes, E=800000 edges, 128->128(relu)->64.
// CSR build: two-level LDS-binned partition (128-node buckets, no global
// atomics), launch-fused. GEMMs: fp16 MFMA 16x16x32, LDS-free, prepacked W.
// agg1: 32-lane segment per node, uint2 lanes (256B/row), width-32 shuffles.
// agg2: 32-lane segment per node, uint lanes (128B/row). f32 accumulation.

#define CHUNK 4096   // edges per partition chunk
#define BSHIFT 7
#define BSIZE 128    // nodes per bucket
#define BCAP 4096    // max edges per bucket held in LDS (avg ~2046)

typedef unsigned int uint;
typedef _Float16 f16x8 __attribute__((ext_vector_type(8)));
typedef float f32x4 __attribute__((ext_vector_type(4)));

__device__ __forceinline__ float2 h2f(uint v) {
  __half2 h;
  __builtin_memcpy(&h, &v, 4);
  return __half22float2(h);
}

__device__ __forceinline__ uint f2h(float a, float b) {
  __half2 h = __halves2half2(__float2half_rn(a), __float2half_rn(b));
  uint r;
  __builtin_memcpy(&r, &h, 4);
  return r;
}

// int64-vs-int32 detection per block: wave-0 ballot over first 64 high words.
__device__ __forceinline__ int block_is64(const int* ei, int* s_is64) {
  if (threadIdx.x < 64) {
    unsigned long long m = __ballot(ei[2 * threadIdx.x + 1] != 0);
    if (threadIdx.x == 0) *s_is64 = (m == 0ULL) ? 1 : 0;
  }
  __syncthreads();
  return *s_is64;
}

// A1 (+fused W-prep): blocks < nchunk do per-chunk histogram over buckets
// (dst>>BSHIFT); blocks >= nchunk pack W1/W2 into fragment-linear fp16.
__global__ __launch_bounds__(256) void hist_prep_k(const int* __restrict__ ei,
                                                   int* __restrict__ gh,
                                                   const float* __restrict__ W1,
                                                   const float* __restrict__ W2,
                                                   _Float16* __restrict__ P,
                                                   int E, int nchunk, int nbuck) {
  if (blockIdx.x >= nchunk) {
    int li = (blockIdx.x - nchunk) * 256 + threadIdx.x;  // 0..24575
    if (li >= 24576) return;
    const float* W;
    _Float16* dst;
    int NC, idx;
    if (li < 16384) { W = W1; dst = P;         NC = 128; idx = li; }
    else            { W = W2; dst = P + 16384; NC = 64;  idx = li - 16384; }
    int NF = NC >> 4;
    int j = idx & 7;
    int l = (idx >> 3) & 63;
    int rest = idx >> 9;
    int c = rest % NF;
    int t = rest / NF;
    int k = t * 32 + ((l >> 4) << 3) + j;
    int col = c * 16 + (l & 15);
    dst[idx] = (_Float16)W[(size_t)k * NC + col];
    return;
  }
  __shared__ int h[512];
  __shared__ int s_is64;
  int c = blockIdx.x;
  for (int i = threadIdx.x; i < 512; i += 256) h[i] = 0;
  int is64 = block_is64(ei, &s_is64);  // includes __syncthreads
  int base = c * CHUNK;
  int lim = min(CHUNK, E - base);
  for (int i = threadIdx.x; i < lim; i += 256) {
    int e = base + i;
    int d = is64 ? ei[2 * ((size_t)E + e)] : ei[(size_t)E + e];
    atomicAdd(&h[d >> BSHIFT], 1);
  }
  __syncthreads();
  for (int k = threadIdx.x; k < nbuck; k += 256) gh[k * nchunk + c] = h[k];
}

// A2 (fused totals+scan): block k sums gh[0 .. k*nchunk) -> bucketStart[k],
// then scans its own row into SEPARATE gbase (gh is read-only -> no race).
__global__ __launch_bounds__(256) void scanrow_k(const int* __restrict__ gh,
                                                 int* __restrict__ gbase,
                                                 int* __restrict__ bucketStart,
                                                 int* __restrict__ offsets,
                                                 int nchunk, int nbuck, int N, int E) {
  __shared__ int st[256];
  int k = blockIdx.x;
  int t = threadIdx.x;
  int tot = k * nchunk;
  int partial = 0;
  for (int i = t; i < tot; i += 256) partial += gh[i];
  st[t] = partial;
  __syncthreads();
  for (int o = 128; o > 0; o >>= 1) {
    if (t < o) st[t] += st[t + o];
    __syncthreads();
  }
  int bs = st[0];
  if (t == 0) {
    bucketStart[k] = bs;
    if (k == nbuck - 1) { bucketStart[nbuck] = E; offsets[N] = E; }
  }
  __syncthreads();
  int x = (t < nchunk) ? gh[k * nchunk + t] : 0;
  st[t] = x;
  __syncthreads();
  int incl = x;
  for (int o = 1; o < 256; o <<= 1) {
    int add = (t >= o) ? st[t - o] : 0;
    __syncthreads();
    incl += add;
    st[t] = incl;
    __syncthreads();
  }
  if (t < nchunk) gbase[k * nchunk + t] = bs + (incl - x);
}

// A3: partition edges into bucket-grouped tmp, packed (src16 | dstlow7<<16)
__global__ __launch_bounds__(256) void part_k(const int* __restrict__ ei,
                                              const int* __restrict__ gbase,
                                              int* __restrict__ tmp,
                                              int E, int nchunk, int nbuck) {
  __shared__ int cur[512];
  __shared__ int s_is64;
  int c = blockIdx.x;
  for (int i = threadIdx.x; i < nbuck; i += 256) cur[i] = gbase[i * nchunk + c];
  int is64 = block_is64(ei, &s_is64);
  int base = c * CHUNK;
  int lim = min(CHUNK, E - base);
  for (int i = threadIdx.x; i < lim; i += 256) {
    int e = base + i;
    int s, d;
    if (is64) {
      s = ei[2 * (size_t)e];
      d = ei[2 * ((size_t)E + e)];
    } else {
      s = ei[e];
      d = ei[(size_t)E + e];
    }
    int p = atomicAdd(&cur[d >> BSHIFT], 1);
    tmp[p] = s | ((d & (BSIZE - 1)) << 16);
  }
}

// B: one block per 128-node bucket: LDS count+scan -> offsets, dinv, csr_src
__global__ __launch_bounds__(256) void bucket_k(const int* __restrict__ tmp,
                                                const int* __restrict__ bucketStart,
                                                int* __restrict__ csr_src,
                                                int* __restrict__ offsets,
                                                float* __restrict__ dinv,
                                                int N) {
  __shared__ int ebuf[BCAP];
  __shared__ int cnt[BSIZE];
  __shared__ int st[256];
  __shared__ int lofs[BSIZE];
  int k = blockIdx.x;
  int b0 = bucketStart[k], b1 = bucketStart[k + 1];
  int sz = b1 - b0;
  int t = threadIdx.x;
  if (t < BSIZE) cnt[t] = 0;
  __syncthreads();
  bool inlds = (sz <= BCAP);
  if (inlds) {
    for (int i = t; i < sz; i += 256) {
      int v = tmp[b0 + i];
      ebuf[i] = v;
      atomicAdd(&cnt[v >> 16], 1);
    }
  } else {
    for (int i = t; i < sz; i += 256) atomicAdd(&cnt[tmp[b0 + i] >> 16], 1);
  }
  __syncthreads();
  int x = (t < BSIZE) ? cnt[t] : 0;
  st[t] = x;
  __syncthreads();
  int incl = x;
  for (int o = 1; o < 256; o <<= 1) {
    int add = (t >= o) ? st[t - o] : 0;
    __syncthreads();
    incl += add;
    st[t] = incl;
    __syncthreads();
  }
  int node = (k << BSHIFT) + t;
  if (t < BSIZE) {
    lofs[t] = incl - x;
    if (node < N) {
      offsets[node] = b0 + lofs[t];
      dinv[node] = rsqrtf((float)(x + 1));  // +1 self-loop
    }
  }
  __syncthreads();
  if (t < BSIZE) cnt[t] = lofs[t];  // reuse as cursor
  __syncthreads();
  if (inlds) {
    for (int i = t; i < sz; i += 256) {
      int v = ebuf[i];
      int p = atomicAdd(&cnt[v >> 16], 1);
      csr_src[b0 + p] = v & 0xFFFF;
    }
  } else {
    for (int i = t; i < sz; i += 256) {
      int v = tmp[b0 + i];
      int p = atomicAdd(&cnt[v >> 16], 1);
      csr_src[b0 + p] = v & 0xFFFF;
    }
  }
}

// ---- MFMA GEMM: H(fp16 row-major) = dinv[row] * (X[M,128] @ W[128,NC]) ----
// 4 waves/block, wave w: rows blk*64 + w*16. No LDS.
template <int NC, bool A16>
__global__ __launch_bounds__(256) void mfma_gemm_k(const void* __restrict__ Xv,
                                                   const _Float16* __restrict__ Wp,
                                                   const float* __restrict__ dinv,
                                                   _Float16* __restrict__ H, int M) {
  constexpr int NF = NC / 16;
  int lane = threadIdx.x & 63;
  int w = threadIdx.x >> 6;
  int row0 = blockIdx.x * 64 + w * 16;
  int arow = row0 + (lane & 15);
  bool av = arow < M;
  const uint4* wp = (const uint4*)Wp;

  f32x4 acc[NF];
#pragma unroll
  for (int c = 0; c < NF; ++c) acc[c] = (f32x4){0.f, 0.f, 0.f, 0.f};

#pragma unroll
  for (int t = 0; t < 4; ++t) {
    f16x8 a;
    if constexpr (A16) {
      const _Float16* xr = (const _Float16*)Xv + (size_t)arow * 128 + ((lane >> 4) << 3);
      uint4 araw = av ? *(const uint4*)(xr + t * 32) : make_uint4(0u, 0u, 0u, 0u);
      __builtin_memcpy(&a, &araw, 16);
    } else {
      const float* xr = (const float*)Xv + (size_t)arow * 128 + ((lane >> 4) << 3);
      float4 lo = av ? *(const float4*)(xr + t * 32) : make_float4(0.f, 0.f, 0.f, 0.f);
      float4 hi = av ? *(const float4*)(xr + t * 32 + 4) : make_float4(0.f, 0.f, 0.f, 0.f);
      a[0] = (_Float16)lo.x; a[1] = (_Float16)lo.y;
      a[2] = (_Float16)lo.z; a[3] = (_Float16)lo.w;
      a[4] = (_Float16)hi.x; a[5] = (_Float16)hi.y;
      a[6] = (_Float16)hi.z; a[7] = (_Float16)hi.w;
    }
#pragma unroll
    for (int c = 0; c < NF; ++c) {
      uint4 braw = wp[(t * NF + c) * 64 + lane];
      f16x8 b;
      __builtin_memcpy(&b, &braw, 16);
      acc[c] = __builtin_amdgcn_mfma_f32_16x16x32_f16(a, b, acc[c], 0, 0, 0);
    }
  }

  int rbase = row0 + ((lane >> 4) << 2);
#pragma unroll
  for (int r = 0; r < 4; ++r) {
    int row = rbase + r;
    if (row < M) {
      float di = dinv[row];
#pragma unroll
      for (int c = 0; c < NF; ++c)
        H[(size_t)row * NC + c * 16 + (lane & 15)] = (_Float16)(di * acc[c][r]);
    }
  }
}

// ---- agg1: y[i](fp16) = relu( dinv_i*(h'_i + sum_src h'_src) + b1 ), 128 f ----
// h' rows: 32 uint2 (fp16x4) = 256B. One 32-lane SEGMENT per node (2/wave):
// trip counts segment-uniform; shuffles width-32. Lane fl holds feats 4fl..4fl+3.
__global__ __launch_bounds__(256) void agg1_k(const uint2* __restrict__ hp,
                                              const float* __restrict__ dinv,
                                              const int* __restrict__ offsets,
                                              const int* __restrict__ csr_src,
                                              const float* __restrict__ b,
                                              uint2* __restrict__ y, int n) {
  int wv = threadIdx.x >> 6;
  int lane = threadIdx.x & 63;
  int half = lane >> 5;
  int fl = lane & 31;
  int node = blockIdx.x * 8 + wv * 2 + half;
  if (node >= n) return;  // uniform within segment
  int beg = offsets[node], end = offsets[node + 1];
  int deg = end - beg;
  uint2 su = hp[(size_t)node * 32 + fl];
  float2 sl = h2f(su.x), sh = h2f(su.y);
  float a0 = sl.x, a1 = sl.y, a2 = sh.x, a3 = sh.y;
  int sv = 0;
  if (fl < deg) sv = csr_src[beg + fl];
  int lim = deg < 32 ? deg : 32;
  int e = 0;
  for (; e + 8 <= lim; e += 8) {
    int sA = __shfl(sv, e + 0, 32), sB = __shfl(sv, e + 1, 32);
    int sC = __shfl(sv, e + 2, 32), sD = __shfl(sv, e + 3, 32);
    int sE = __shfl(sv, e + 4, 32), sF = __shfl(sv, e + 5, 32);
    int sG = __shfl(sv, e + 6, 32), sH = __shfl(sv, e + 7, 32);
    uint2 uA = hp[(size_t)sA * 32 + fl];
    uint2 uB = hp[(size_t)sB * 32 + fl];
    uint2 uC = hp[(size_t)sC * 32 + fl];
    uint2 uD = hp[(size_t)sD * 32 + fl];
    uint2 uE = hp[(size_t)sE * 32 + fl];
    uint2 uF = hp[(size_t)sF * 32 + fl];
    uint2 uG = hp[(size_t)sG * 32 + fl];
    uint2 uH = hp[(size_t)sH * 32 + fl];
    float2 lA = h2f(uA.x), hA = h2f(uA.y), lB = h2f(uB.x), hB = h2f(uB.y);
    float2 lC = h2f(uC.x), hC = h2f(uC.y), lD = h2f(uD.x), hD = h2f(uD.y);
    float2 lE = h2f(uE.x), hE = h2f(uE.y), lF = h2f(uF.x), hF = h2f(uF.y);
    float2 lG = h2f(uG.x), hG = h2f(uG.y), lH = h2f(uH.x), hH = h2f(uH.y);
    a0 += ((lA.x + lB.x) + (lC.x + lD.x)) + ((lE.x + lF.x) + (lG.x + lH.x));
    a1 += ((lA.y + lB.y) + (lC.y + lD.y)) + ((lE.y + lF.y) + (lG.y + lH.y));
    a2 += ((hA.x + hB.x) + (hC.x + hD.x)) + ((hE.x + hF.x) + (hG.x + hH.x));
    a3 += ((hA.y + hB.y) + (hC.y + hD.y)) + ((hE.y + hF.y) + (hG.y + hH.y));
  }
  for (; e < lim; ++e) {
    int s = __shfl(sv, e, 32);
    uint2 u = hp[(size_t)s * 32 + fl];
    float2 l = h2f(u.x), h = h2f(u.y);
    a0 += l.x; a1 += l.y; a2 += h.x; a3 += h.y;
  }
  for (int ee = beg + 32; ee < end; ++ee) {  // deg>32 fallback (rare, uniform)
    uint2 u = hp[(size_t)csr_src[ee] * 32 + fl];
    float2 l = h2f(u.x), h = h2f(u.y);
    a0 += l.x; a1 += l.y; a2 += h.x; a3 += h.y;
  }
  float di = dinv[node];
  float4 bb = *(const float4*)(b + 4 * fl);
  float o0 = fmaxf(fmaf(di, a0, bb.x), 0.f);
  float o1 = fmaxf(fmaf(di, a1, bb.y), 0.f);
  float o2 = fmaxf(fmaf(di, a2, bb.z), 0.f);
  float o3 = fmaxf(fmaf(di, a3, bb.w), 0.f);
  uint2 o;
  o.x = f2h(o0, o1);
  o.y = f2h(o2, o3);
  y[(size_t)node * 32 + fl] = o;
}

// ---- agg2: out[i](f32) = dinv_i*(h'_i + sum_src h'_src) + b2, 64 feats ----
// h' rows: 32 uints (fp16x2) = 128B. One 32-lane segment per node.
__global__ __launch_bounds__(256) void agg2_k(const uint* __restrict__ hp,
                                              const float* __restrict__ dinv,
                                              const int* __restrict__ offsets,
                                              const int* __restrict__ csr_src,
                                              const float* __restrict__ b,
                                              float* __restrict__ out, int n) {
  int wv = threadIdx.x >> 6;
  int lane = threadIdx.x & 63;
  int half = lane >> 5;
  int fl = lane & 31;
  int node = blockIdx.x * 8 + wv * 2 + half;
  if (node >= n) return;
  int beg = offsets[node], end = offsets[node + 1];
  int deg = end - beg;
  float2 self = h2f(hp[(size_t)node * 32 + fl]);
  float ax = self.x, ay = self.y;
  int sv = 0;
  if (fl < deg) sv = csr_src[beg + fl];
  int lim = deg < 32 ? deg : 32;
  int e = 0;
  for (; e + 8 <= lim; e += 8) {
    int s0 = __shfl(sv, e + 0, 32), s1 = __shfl(sv, e + 1, 32);
    int s2 = __shfl(sv, e + 2, 32), s3 = __shfl(sv, e + 3, 32);
    int s4 = __shfl(sv, e + 4, 32), s5 = __shfl(sv, e + 5, 32);
    int s6 = __shfl(sv, e + 6, 32), s7 = __shfl(sv, e + 7, 32);
    uint u0 = hp[(size_t)s0 * 32 + fl];
    uint u1 = hp[(size_t)s1 * 32 + fl];
    uint u2 = hp[(size_t)s2 * 32 + fl];
    uint u3 = hp[(size_t)s3 * 32 + fl];
    uint u4 = hp[(size_t)s4 * 32 + fl];
    uint u5 = hp[(size_t)s5 * 32 + fl];
    uint u6 = hp[(size_t)s6 * 32 + fl];
    uint u7 = hp[(size_t)s7 * 32 + fl];
    float2 v0 = h2f(u0), v1 = h2f(u1), v2 = h2f(u2), v3 = h2f(u3);
    float2 v4 = h2f(u4), v5 = h2f(u5), v6 = h2f(u6), v7 = h2f(u7);
    ax += ((v0.x + v1.x) + (v2.x + v3.x)) + ((v4.x + v5.x) + (v6.x + v7.x));
    ay += ((v0.y + v1.y) + (v2.y + v3.y)) + ((v4.y + v5.y) + (v6.y + v7.y));
  }
  for (; e < lim; ++e) {
    int s = __shfl(sv, e, 32);
    float2 v = h2f(hp[(size_t)s * 32 + fl]);
    ax += v.x;
    ay += v.y;
  }
  for (int ee = beg + 32; ee < end; ++ee) {
    float2 v = h2f(hp[(size_t)csr_src[ee] * 32 + fl]);
    ax += v.x;
    ay += v.y;
  }
  float di = dinv[node];
  float2 bb = ((const float2*)b)[fl];
  float2 o;
  o.x = fmaf(di, ax, bb.x);
  o.y = fmaf(di, ay, bb.y);
  ((float2*)out)[(size_t)node * 32 + fl] = o;
}

extern "C" void kernel_launch(void* const* d_in, const int* in_sizes, int n_in,
                              void* d_out, int out_size, void* d_ws, size_t ws_size,
                              hipStream_t stream) {
  const float* x  = (const float*)d_in[0];
  const int*   ei = (const int*)d_in[1];
  const float* W1 = (const float*)d_in[2];
  const float* b1 = (const float*)d_in[3];
  const float* W2 = (const float*)d_in[4];
  const float* b2 = (const float*)d_in[5];
  float* out = (float*)d_out;

  const int N = in_sizes[0] / 128;   // 50000
  const int E = in_sizes[1] / 2;     // 800000
  const int NBUCK = (N + BSIZE - 1) >> BSHIFT;   // 391
  const int NCHUNK = (E + CHUNK - 1) / CHUNK;    // 196

  char* w = (char*)d_ws;
  size_t off = 0;
  auto alloc = [&](size_t bytes) -> void* {
    void* p = w + off;
    off = (off + bytes + 511) & ~(size_t)511;
    return p;
  };
  int*       gh      = (int*)alloc((size_t)NBUCK * NCHUNK * 4);
  int*       gbase   = (int*)alloc((size_t)NBUCK * NCHUNK * 4);
  int*       bstart  = (int*)alloc((size_t)(NBUCK + 1) * 4);
  int*       tmp     = (int*)alloc((size_t)E * 4);
  int*       offsets = (int*)alloc((size_t)(N + 1) * 4);
  float*     dinv    = (float*)alloc((size_t)N * 4);
  int*       csr_src = (int*)alloc((size_t)E * 4);
  _Float16*  pW      = (_Float16*)alloc(24576 * 2);            // W1|W2 packs
  _Float16*  h1      = (_Float16*)alloc((size_t)N * 128 * 2);  // fp16 row-major
  _Float16*  y       = (_Float16*)alloc((size_t)N * 128 * 2);  // fp16 row-major
  _Float16*  h2      = (_Float16*)alloc((size_t)N * 64 * 2);   // fp16 row-major

  const int GB  = (N + 63) / 64;
  const int AB  = (N + 7) / 8;   // 8 nodes per block (2 per wave)

  hist_prep_k<<<NCHUNK + 96, 256, 0, stream>>>(ei, gh, W1, W2, pW, E, NCHUNK, NBUCK);
  scanrow_k<<<NBUCK, 256, 0, stream>>>(gh, gbase, bstart, offsets, NCHUNK, NBUCK, N, E);
  part_k<<<NCHUNK, 256, 0, stream>>>(ei, gbase, tmp, E, NCHUNK, NBUCK);
  bucket_k<<<NBUCK, 256, 0, stream>>>(tmp, bstart, csr_src, offsets, dinv, N);

  mfma_gemm_k<128, false><<<GB, 256, 0, stream>>>(x, pW, dinv, h1, N);
  agg1_k<<<AB, 256, 0, stream>>>((const uint2*)h1, dinv, offsets, csr_src, b1,
                                 (uint2*)y, N);
  mfma_gemm_k<64, true><<<GB, 256, 0, stream>>>(y, pW + 16384, dinv, h2, N);
  agg2_k<<<AB, 256, 0, stream>>>((const uint*)h2, dinv, offsets, csr_src, b2, out, N);
}

// Round 11
// 105.508 us; speedup vs baseline: 1.5520x; 1.3374x over previous
//
#include <hip/hip_runtime.h>
#include <hip/hip_bf16.h>
#include <hip/hip_fp16.h>

// GCN 2-layer: N=50000 nodes, E=800000 edges, 128->128(relu)->64.
// CSR build: two-level LDS-binned partition (128-node buckets, no global
// atomics). GEMMs: fp16 MFMA 16x16x32, LDS-free, prepacked W.
// agg1: 32-lane segment per node, uint2 lanes (256B/row), width-32 shuffles.
// agg2: 32-lane segment per node, uint lanes (128B/row). f32 accumulation.

#define CHUNK 4096   // edges per partition chunk
#define BSHIFT 7
#define BSIZE 128    // nodes per bucket
#define BCAP 4096    // max edges per bucket held in LDS (avg ~2046)

typedef unsigned int uint;
typedef _Float16 f16x8 __attribute__((ext_vector_type(8)));
typedef float f32x4 __attribute__((ext_vector_type(4)));

__device__ __forceinline__ float2 h2f(uint v) {
  __half2 h;
  __builtin_memcpy(&h, &v, 4);
  return __half22float2(h);
}

__device__ __forceinline__ uint f2h(float a, float b) {
  __half2 h = __halves2half2(__float2half_rn(a), __float2half_rn(b));
  uint r;
  __builtin_memcpy(&r, &h, 4);
  return r;
}

// int64-vs-int32 detection per block: wave-0 ballot over first 64 high words.
__device__ __forceinline__ int block_is64(const int* ei, int* s_is64) {
  if (threadIdx.x < 64) {
    unsigned long long m = __ballot(ei[2 * threadIdx.x + 1] != 0);
    if (threadIdx.x == 0) *s_is64 = (m == 0ULL) ? 1 : 0;
  }
  __syncthreads();
  return *s_is64;
}

// A1 (+fused W-prep): blocks < nchunk do per-chunk histogram over buckets
// (dst>>BSHIFT); blocks >= nchunk pack W1/W2 into fragment-linear fp16.
__global__ __launch_bounds__(256) void hist_prep_k(const int* __restrict__ ei,
                                                   int* __restrict__ gh,
                                                   const float* __restrict__ W1,
                                                   const float* __restrict__ W2,
                                                   _Float16* __restrict__ P,
                                                   int E, int nchunk, int nbuck) {
  if (blockIdx.x >= nchunk) {
    int li = (blockIdx.x - nchunk) * 256 + threadIdx.x;  // 0..24575
    if (li >= 24576) return;
    const float* W;
    _Float16* dst;
    int NC, idx;
    if (li < 16384) { W = W1; dst = P;         NC = 128; idx = li; }
    else            { W = W2; dst = P + 16384; NC = 64;  idx = li - 16384; }
    int NF = NC >> 4;
    int j = idx & 7;
    int l = (idx >> 3) & 63;
    int rest = idx >> 9;
    int c = rest % NF;
    int t = rest / NF;
    int k = t * 32 + ((l >> 4) << 3) + j;
    int col = c * 16 + (l & 15);
    dst[idx] = (_Float16)W[(size_t)k * NC + col];
    return;
  }
  __shared__ int h[512];
  __shared__ int s_is64;
  int c = blockIdx.x;
  for (int i = threadIdx.x; i < 512; i += 256) h[i] = 0;
  int is64 = block_is64(ei, &s_is64);  // includes __syncthreads
  int base = c * CHUNK;
  int lim = min(CHUNK, E - base);
  for (int i = threadIdx.x; i < lim; i += 256) {
    int e = base + i;
    int d = is64 ? ei[2 * ((size_t)E + e)] : ei[(size_t)E + e];
    atomicAdd(&h[d >> BSHIFT], 1);
  }
  __syncthreads();
  for (int k = threadIdx.x; k < nbuck; k += 256) gh[k * nchunk + c] = h[k];
}

// A2a: per-bucket totals (block k sums its gh row)
__global__ __launch_bounds__(256) void tot_k(const int* __restrict__ gh,
                                             int* __restrict__ totals, int nchunk) {
  __shared__ int sd[256];
  int k = blockIdx.x;
  int s = 0;
  for (int i = threadIdx.x; i < nchunk; i += 256) s += gh[k * nchunk + i];
  sd[threadIdx.x] = s;
  __syncthreads();
  for (int o = 128; o > 0; o >>= 1) {
    if (threadIdx.x < o) sd[threadIdx.x] += sd[threadIdx.x + o];
    __syncthreads();
  }
  if (threadIdx.x == 0) totals[k] = sd[0];
}

// A2b: block k: bucketStart[k] (= sum totals[<k]) + scan of row k -> gbase.
__global__ __launch_bounds__(256) void scanrow_k(const int* __restrict__ gh,
                                                 const int* __restrict__ totals,
                                                 int* __restrict__ gbase,
                                                 int* __restrict__ bucketStart,
                                                 int* __restrict__ offsets,
                                                 int nchunk, int nbuck, int N, int E) {
  __shared__ int st[256];
  int k = blockIdx.x;
  int t = threadIdx.x;
  int partial = 0;
  for (int i = t; i < k; i += 256) partial += totals[i];
  st[t] = partial;
  __syncthreads();
  for (int o = 128; o > 0; o >>= 1) {
    if (t < o) st[t] += st[t + o];
    __syncthreads();
  }
  int bs = st[0];
  if (t == 0) {
    bucketStart[k] = bs;
    if (k == nbuck - 1) { bucketStart[nbuck] = E; offsets[N] = E; }
  }
  __syncthreads();
  int x = (t < nchunk) ? gh[k * nchunk + t] : 0;
  st[t] = x;
  __syncthreads();
  int incl = x;
  for (int o = 1; o < 256; o <<= 1) {
    int add = (t >= o) ? st[t - o] : 0;
    __syncthreads();
    incl += add;
    st[t] = incl;
    __syncthreads();
  }
  if (t < nchunk) gbase[k * nchunk + t] = bs + (incl - x);
}

// A3: partition edges into bucket-grouped tmp, packed (src16 | dstlow7<<16)
__global__ __launch_bounds__(256) void part_k(const int* __restrict__ ei,
                                              const int* __restrict__ gbase,
                                              int* __restrict__ tmp,
                                              int E, int nchunk, int nbuck) {
  __shared__ int cur[512];
  __shared__ int s_is64;
  int c = blockIdx.x;
  for (int i = threadIdx.x; i < nbuck; i += 256) cur[i] = gbase[i * nchunk + c];
  int is64 = block_is64(ei, &s_is64);
  int base = c * CHUNK;
  int lim = min(CHUNK, E - base);
  for (int i = threadIdx.x; i < lim; i += 256) {
    int e = base + i;
    int s, d;
    if (is64) {
      s = ei[2 * (size_t)e];
      d = ei[2 * ((size_t)E + e)];
    } else {
      s = ei[e];
      d = ei[(size_t)E + e];
    }
    int p = atomicAdd(&cur[d >> BSHIFT], 1);
    tmp[p] = s | ((d & (BSIZE - 1)) << 16);
  }
}

// B: one block per 128-node bucket: LDS count+scan -> offsets, dinv, csr_src
__global__ __launch_bounds__(256) void bucket_k(const int* __restrict__ tmp,
                                                const int* __restrict__ bucketStart,
                                                int* __restrict__ csr_src,
                                                int* __restrict__ offsets,
                                                float* __restrict__ dinv,
                                                int N) {
  __shared__ int ebuf[BCAP];
  __shared__ int cnt[BSIZE];
  __shared__ int st[256];
  __shared__ int lofs[BSIZE];
  int k = blockIdx.x;
  int b0 = bucketStart[k], b1 = bucketStart[k + 1];
  int sz = b1 - b0;
  int t = threadIdx.x;
  if (t < BSIZE) cnt[t] = 0;
  __syncthreads();
  bool inlds = (sz <= BCAP);
  if (inlds) {
    for (int i = t; i < sz; i += 256) {
      int v = tmp[b0 + i];
      ebuf[i] = v;
      atomicAdd(&cnt[v >> 16], 1);
    }
  } else {
    for (int i = t; i < sz; i += 256) atomicAdd(&cnt[tmp[b0 + i] >> 16], 1);
  }
  __syncthreads();
  int x = (t < BSIZE) ? cnt[t] : 0;
  st[t] = x;
  __syncthreads();
  int incl = x;
  for (int o = 1; o < 256; o <<= 1) {
    int add = (t >= o) ? st[t - o] : 0;
    __syncthreads();
    incl += add;
    st[t] = incl;
    __syncthreads();
  }
  int node = (k << BSHIFT) + t;
  if (t < BSIZE) {
    lofs[t] = incl - x;
    if (node < N) {
      offsets[node] = b0 + lofs[t];
      dinv[node] = rsqrtf((float)(x + 1));  // +1 self-loop
    }
  }
  __syncthreads();
  if (t < BSIZE) cnt[t] = lofs[t];  // reuse as cursor
  __syncthreads();
  if (inlds) {
    for (int i = t; i < sz; i += 256) {
      int v = ebuf[i];
      int p = atomicAdd(&cnt[v >> 16], 1);
      csr_src[b0 + p] = v & 0xFFFF;
    }
  } else {
    for (int i = t; i < sz; i += 256) {
      int v = tmp[b0 + i];
      int p = atomicAdd(&cnt[v >> 16], 1);
      csr_src[b0 + p] = v & 0xFFFF;
    }
  }
}

// ---- MFMA GEMM: H(fp16 row-major) = dinv[row] * (X[M,128] @ W[128,NC]) ----
// 4 waves/block, wave w: rows blk*64 + w*16. No LDS.
template <int NC, bool A16>
__global__ __launch_bounds__(256) void mfma_gemm_k(const void* __restrict__ Xv,
                                                   const _Float16* __restrict__ Wp,
                                                   const float* __restrict__ dinv,
                                                   _Float16* __restrict__ H, int M) {
  constexpr int NF = NC / 16;
  int lane = threadIdx.x & 63;
  int w = threadIdx.x >> 6;
  int row0 = blockIdx.x * 64 + w * 16;
  int arow = row0 + (lane & 15);
  bool av = arow < M;
  const uint4* wp = (const uint4*)Wp;

  f32x4 acc[NF];
#pragma unroll
  for (int c = 0; c < NF; ++c) acc[c] = (f32x4){0.f, 0.f, 0.f, 0.f};

#pragma unroll
  for (int t = 0; t < 4; ++t) {
    f16x8 a;
    if constexpr (A16) {
      const _Float16* xr = (const _Float16*)Xv + (size_t)arow * 128 + ((lane >> 4) << 3);
      uint4 araw = av ? *(const uint4*)(xr + t * 32) : make_uint4(0u, 0u, 0u, 0u);
      __builtin_memcpy(&a, &araw, 16);
    } else {
      const float* xr = (const float*)Xv + (size_t)arow * 128 + ((lane >> 4) << 3);
      float4 lo = av ? *(const float4*)(xr + t * 32) : make_float4(0.f, 0.f, 0.f, 0.f);
      float4 hi = av ? *(const float4*)(xr + t * 32 + 4) : make_float4(0.f, 0.f, 0.f, 0.f);
      a[0] = (_Float16)lo.x; a[1] = (_Float16)lo.y;
      a[2] = (_Float16)lo.z; a[3] = (_Float16)lo.w;
      a[4] = (_Float16)hi.x; a[5] = (_Float16)hi.y;
      a[6] = (_Float16)hi.z; a[7] = (_Float16)hi.w;
    }
#pragma unroll
    for (int c = 0; c < NF; ++c) {
      uint4 braw = wp[(t * NF + c) * 64 + lane];
      f16x8 b;
      __builtin_memcpy(&b, &braw, 16);
      acc[c] = __builtin_amdgcn_mfma_f32_16x16x32_f16(a, b, acc[c], 0, 0, 0);
    }
  }

  int rbase = row0 + ((lane >> 4) << 2);
#pragma unroll
  for (int r = 0; r < 4; ++r) {
    int row = rbase + r;
    if (row < M) {
      float di = dinv[row];
#pragma unroll
      for (int c = 0; c < NF; ++c)
        H[(size_t)row * NC + c * 16 + (lane & 15)] = (_Float16)(di * acc[c][r]);
    }
  }
}

// ---- agg1: y[i](fp16) = relu( dinv_i*(h'_i + sum_src h'_src) + b1 ), 128 f ----
// h' rows: 32 uint2 (fp16x4) = 256B. One 32-lane SEGMENT per node (2/wave):
// trip counts segment-uniform; shuffles width-32. Lane fl holds feats 4fl..4fl+3.
__global__ __launch_bounds__(256) void agg1_k(const uint2* __restrict__ hp,
                                              const float* __restrict__ dinv,
                                              const int* __restrict__ offsets,
                                              const int* __restrict__ csr_src,
                                              const float* __restrict__ b,
                                              uint2* __restrict__ y, int n) {
  int wv = threadIdx.x >> 6;
  int lane = threadIdx.x & 63;
  int half = lane >> 5;
  int fl = lane & 31;
  int node = blockIdx.x * 8 + wv * 2 + half;
  if (node >= n) return;  // uniform within segment
  int beg = offsets[node], end = offsets[node + 1];
  int deg = end - beg;
  uint2 su = hp[(size_t)node * 32 + fl];
  float2 sl = h2f(su.x), sh = h2f(su.y);
  float a0 = sl.x, a1 = sl.y, a2 = sh.x, a3 = sh.y;
  int sv = 0;
  if (fl < deg) sv = csr_src[beg + fl];
  int lim = deg < 32 ? deg : 32;
  int e = 0;
  for (; e + 8 <= lim; e += 8) {
    int sA = __shfl(sv, e + 0, 32), sB = __shfl(sv, e + 1, 32);
    int sC = __shfl(sv, e + 2, 32), sD = __shfl(sv, e + 3, 32);
    int sE = __shfl(sv, e + 4, 32), sF = __shfl(sv, e + 5, 32);
    int sG = __shfl(sv, e + 6, 32), sH = __shfl(sv, e + 7, 32);
    uint2 uA = hp[(size_t)sA * 32 + fl];
    uint2 uB = hp[(size_t)sB * 32 + fl];
    uint2 uC = hp[(size_t)sC * 32 + fl];
    uint2 uD = hp[(size_t)sD * 32 + fl];
    uint2 uE = hp[(size_t)sE * 32 + fl];
    uint2 uF = hp[(size_t)sF * 32 + fl];
    uint2 uG = hp[(size_t)sG * 32 + fl];
    uint2 uH = hp[(size_t)sH * 32 + fl];
    float2 lA = h2f(uA.x), hA = h2f(uA.y), lB = h2f(uB.x), hB = h2f(uB.y);
    float2 lC = h2f(uC.x), hC = h2f(uC.y), lD = h2f(uD.x), hD = h2f(uD.y);
    float2 lE = h2f(uE.x), hE = h2f(uE.y), lF = h2f(uF.x), hF = h2f(uF.y);
    float2 lG = h2f(uG.x), hG = h2f(uG.y), lH = h2f(uH.x), hH = h2f(uH.y);
    a0 += ((lA.x + lB.x) + (lC.x + lD.x)) + ((lE.x + lF.x) + (lG.x + lH.x));
    a1 += ((lA.y + lB.y) + (lC.y + lD.y)) + ((lE.y + lF.y) + (lG.y + lH.y));
    a2 += ((hA.x + hB.x) + (hC.x + hD.x)) + ((hE.x + hF.x) + (hG.x + hH.x));
    a3 += ((hA.y + hB.y) + (hC.y + hD.y)) + ((hE.y + hF.y) + (hG.y + hH.y));
  }
  for (; e < lim; ++e) {
    int s = __shfl(sv, e, 32);
    uint2 u = hp[(size_t)s * 32 + fl];
    float2 l = h2f(u.x), h = h2f(u.y);
    a0 += l.x; a1 += l.y; a2 += h.x; a3 += h.y;
  }
  for (int ee = beg + 32; ee < end; ++ee) {  // deg>32 fallback (rare, uniform)
    uint2 u = hp[(size_t)csr_src[ee] * 32 + fl];
    float2 l = h2f(u.x), h = h2f(u.y);
    a0 += l.x; a1 += l.y; a2 += h.x; a3 += h.y;
  }
  float di = dinv[node];
  float4 bb = *(const float4*)(b + 4 * fl);
  float o0 = fmaxf(fmaf(di, a0, bb.x), 0.f);
  float o1 = fmaxf(fmaf(di, a1, bb.y), 0.f);
  float o2 = fmaxf(fmaf(di, a2, bb.z), 0.f);
  float o3 = fmaxf(fmaf(di, a3, bb.w), 0.f);
  uint2 o;
  o.x = f2h(o0, o1);
  o.y = f2h(o2, o3);
  y[(size_t)node * 32 + fl] = o;
}

// ---- agg2: out[i](f32) = dinv_i*(h'_i + sum_src h'_src) + b2, 64 feats ----
// h' rows: 32 uints (fp16x2) = 128B. One 32-lane segment per node.
__global__ __launch_bounds__(256) void agg2_k(const uint* __restrict__ hp,
                                              const float* __restrict__ dinv,
                                              const int* __restrict__ offsets,
                                              const int* __restrict__ csr_src,
                                              const float* __restrict__ b,
                                              float* __restrict__ out, int n) {
  int wv = threadIdx.x >> 6;
  int lane = threadIdx.x & 63;
  int half = lane >> 5;
  int fl = lane & 31;
  int node = blockIdx.x * 8 + wv * 2 + half;
  if (node >= n) return;
  int beg = offsets[node], end = offsets[node + 1];
  int deg = end - beg;
  float2 self = h2f(hp[(size_t)node * 32 + fl]);
  float ax = self.x, ay = self.y;
  int sv = 0;
  if (fl < deg) sv = csr_src[beg + fl];
  int lim = deg < 32 ? deg : 32;
  int e = 0;
  for (; e + 8 <= lim; e += 8) {
    int s0 = __shfl(sv, e + 0, 32), s1 = __shfl(sv, e + 1, 32);
    int s2 = __shfl(sv, e + 2, 32), s3 = __shfl(sv, e + 3, 32);
    int s4 = __shfl(sv, e + 4, 32), s5 = __shfl(sv, e + 5, 32);
    int s6 = __shfl(sv, e + 6, 32), s7 = __shfl(sv, e + 7, 32);
    uint u0 = hp[(size_t)s0 * 32 + fl];
    uint u1 = hp[(size_t)s1 * 32 + fl];
    uint u2 = hp[(size_t)s2 * 32 + fl];
    uint u3 = hp[(size_t)s3 * 32 + fl];
    uint u4 = hp[(size_t)s4 * 32 + fl];
    uint u5 = hp[(size_t)s5 * 32 + fl];
    uint u6 = hp[(size_t)s6 * 32 + fl];
    uint u7 = hp[(size_t)s7 * 32 + fl];
    float2 v0 = h2f(u0), v1 = h2f(u1), v2 = h2f(u2), v3 = h2f(u3);
    float2 v4 = h2f(u4), v5 = h2f(u5), v6 = h2f(u6), v7 = h2f(u7);
    ax += ((v0.x + v1.x) + (v2.x + v3.x)) + ((v4.x + v5.x) + (v6.x + v7.x));
    ay += ((v0.y + v1.y) + (v2.y + v3.y)) + ((v4.y + v5.y) + (v6.y + v7.y));
  }
  for (; e < lim; ++e) {
    int s = __shfl(sv, e, 32);
    float2 v = h2f(hp[(size_t)s * 32 + fl]);
    ax += v.x;
    ay += v.y;
  }
  for (int ee = beg + 32; ee < end; ++ee) {
    float2 v = h2f(hp[(size_t)csr_src[ee] * 32 + fl]);
    ax += v.x;
    ay += v.y;
  }
  float di = dinv[node];
  float2 bb = ((const float2*)b)[fl];
  float2 o;
  o.x = fmaf(di, ax, bb.x);
  o.y = fmaf(di, ay, bb.y);
  ((float2*)out)[(size_t)node * 32 + fl] = o;
}

extern "C" void kernel_launch(void* const* d_in, const int* in_sizes, int n_in,
                              void* d_out, int out_size, void* d_ws, size_t ws_size,
                              hipStream_t stream) {
  const float* x  = (const float*)d_in[0];
  const int*   ei = (const int*)d_in[1];
  const float* W1 = (const float*)d_in[2];
  const float* b1 = (const float*)d_in[3];
  const float* W2 = (const float*)d_in[4];
  const float* b2 = (const float*)d_in[5];
  float* out = (float*)d_out;

  const int N = in_sizes[0] / 128;   // 50000
  const int E = in_sizes[1] / 2;     // 800000
  const int NBUCK = (N + BSIZE - 1) >> BSHIFT;   // 391
  const int NCHUNK = (E + CHUNK - 1) / CHUNK;    // 196

  char* w = (char*)d_ws;
  size_t off = 0;
  auto alloc = [&](size_t bytes) -> void* {
    void* p = w + off;
    off = (off + bytes + 511) & ~(size_t)511;
    return p;
  };
  int*       gh      = (int*)alloc((size_t)NBUCK * NCHUNK * 4);
  int*       gbase   = (int*)alloc((size_t)NBUCK * NCHUNK * 4);
  int*       totals  = (int*)alloc((size_t)NBUCK * 4);
  int*       bstart  = (int*)alloc((size_t)(NBUCK + 1) * 4);
  int*       tmp     = (int*)alloc((size_t)E * 4);
  int*       offsets = (int*)alloc((size_t)(N + 1) * 4);
  float*     dinv    = (float*)alloc((size_t)N * 4);
  int*       csr_src = (int*)alloc((size_t)E * 4);
  _Float16*  pW      = (_Float16*)alloc(24576 * 2);            // W1|W2 packs
  _Float16*  h1      = (_Float16*)alloc((size_t)N * 128 * 2);  // fp16 row-major
  _Float16*  y       = (_Float16*)alloc((size_t)N * 128 * 2);  // fp16 row-major
  _Float16*  h2      = (_Float16*)alloc((size_t)N * 64 * 2);   // fp16 row-major

  const int GB  = (N + 63) / 64;
  const int AB  = (N + 7) / 8;   // 8 nodes per block (2 per wave)

  hist_prep_k<<<NCHUNK + 96, 256, 0, stream>>>(ei, gh, W1, W2, pW, E, NCHUNK, NBUCK);
  tot_k<<<NBUCK, 256, 0, stream>>>(gh, totals, NCHUNK);
  scanrow_k<<<NBUCK, 256, 0, stream>>>(gh, totals, gbase, bstart, offsets,
                                       NCHUNK, NBUCK, N, E);
  part_k<<<NCHUNK, 256, 0, stream>>>(ei, gbase, tmp, E, NCHUNK, NBUCK);
  bucket_k<<<NBUCK, 256, 0, stream>>>(tmp, bstart, csr_src, offsets, dinv, N);

  mfma_gemm_k<128, false><<<GB, 256, 0, stream>>>(x, pW, dinv, h1, N);
  agg1_k<<<AB, 256, 0, stream>>>((const uint2*)h1, dinv, offsets, csr_src, b1,
                                 (uint2*)y, N);
  mfma_gemm_k<64, true><<<GB, 256, 0, stream>>>(y, pW + 16384, dinv, h2, N);
  agg2_k<<<AB, 256, 0, stream>>>((const uint*)h2, dinv, offsets, csr_src, b2, out, N);
}